// Round 4
// baseline (124.673 us; speedup 1.0000x reference)
//
#include <hip/hip_runtime.h>
#include <stdint.h>

// ConvMemory: out = (3x3 conv of E=exp(x), weights=memory) / (3x3 boxsum of channel-sum(E))
// Zero-padding before softmax => OOB taps contribute exp(0)=1 to num & denom.
// Phase A (exp_tr3): NCHW f32 -> NHWC bf16 Et + per-pixel channel sum S.
// Phase B (conv3): implicit-GEMM conv, mfma_f32_32x32x16_bf16 with SWAPPED
//   roles (A=weights m=n_out, B=E n=pixel) so the epilogue writes full 64B
//   segments and Zinv is a per-lane scalar. 1024 blocks of 256 thr, 4/CU.

#define Cn 64
#define Hn 128
#define Wn 128
#define OC 128
#define HW (Hn * Wn)

typedef __attribute__((ext_vector_type(8))) short bf16x8_t;
typedef __attribute__((ext_vector_type(4))) float f32x4_t;
typedef __attribute__((ext_vector_type(16))) float f32x16_t;

__device__ inline unsigned short f2bf(float f) {
    union { float f; uint32_t u; } v; v.f = f;
    uint32_t u = v.u;
    u += 0x7fffu + ((u >> 16) & 1u);
    return (unsigned short)(u >> 16);
}
__device__ inline float bf2f(unsigned short h) {
    union { uint32_t u; float f; } v; v.u = ((uint32_t)h) << 16;
    return v.f;
}

// ---------------------------------------------------------------------------
// prep: memory[576][128] f32 -> Bt2 bf16 chunks: chunk cid=(kc*2+hi), 128 n's,
// 16B per n = 8 channels c = (kc&3)*16 + hi*8 + j, q = kc>>2 (kh*3+kw).
// Block 36 writes the 128B "ones page" (bf16 1.0) used for OOB halo pixels.
// ---------------------------------------------------------------------------
__global__ void prep_b2(const float* __restrict__ mem, uint4* __restrict__ Bt2,
                        uint4* __restrict__ ones) {
    if (blockIdx.x == 36) {
        if (threadIdx.x < 8)
            ones[threadIdx.x] = make_uint4(0x3F803F80u, 0x3F803F80u, 0x3F803F80u, 0x3F803F80u);
        return;
    }
    int u = blockIdx.x * 256 + threadIdx.x;   // 0..9215
    int n = u & 127;
    int cid = u >> 7;                         // 0..71
    int hi = cid & 1;
    int kc = cid >> 1;                        // 0..35
    int q = kc >> 2, cblk = kc & 3;
    unsigned short h8[8];
#pragma unroll
    for (int j = 0; j < 8; j++) {
        int c = cblk * 16 + hi * 8 + j;
        h8[j] = f2bf(mem[(c * 9 + q) * OC + n]);
    }
    Bt2[cid * 128 + n] = *(const uint4*)h8;
}

// ---------------------------------------------------------------------------
// Phase A: per (b,h) row. Waves read channel rows coalesced (512B/instr),
// exp -> bf16 pair-packed into LDS [64][136 shorts] (u32 writes, 2-way=free).
// Phase 2: thread t -> pixel w=t&127, channels ch0=(t>>7)*32 .. +31: pack
// 64B (4 uint4) of NHWC Et + partial channel sum; S combined via LDS.
// ---------------------------------------------------------------------------
__global__ __launch_bounds__(256) void exp_tr3(const float* __restrict__ x,
                                               uint4* __restrict__ Etu,
                                               float* __restrict__ S) {
    __shared__ uint32_t lu[64 * 68];     // 64 ch x 136 shorts (pad 128->136)
    __shared__ float Spart[256];
    int bid = blockIdx.x;            // 1024 = 8 b * 128 h
    int b = bid >> 7, h = bid & 127;
    int t = threadIdx.x;
    int wv = t >> 6, lane = t & 63;

    const float* xr = x + (size_t)b * Cn * HW + h * Wn;
#pragma unroll
    for (int i = 0; i < 16; i++) {
        int c = i * 4 + wv;
        float2 v = *(const float2*)(xr + (size_t)c * HW + lane * 2);
        uint32_t pk = (uint32_t)f2bf(__expf(v.x)) | ((uint32_t)f2bf(__expf(v.y)) << 16);
        lu[c * 68 + lane] = pk;
    }
    __syncthreads();

    const unsigned short* Lp = (const unsigned short*)lu;
    int w = t & 127, ch0 = (t >> 7) * 32;
    unsigned short us[32];
    float s = 0.f;
#pragma unroll
    for (int j = 0; j < 32; j++) {
        unsigned short hb = Lp[(ch0 + j) * 136 + w];
        us[j] = hb;
        s += bf2f(hb);
    }
    size_t pix = (size_t)(b * Hn + h) * Wn + w;
    uint4* dst = Etu + pix * 8 + (t >> 7) * 4;
    const uint4* srcv = (const uint4*)us;
    dst[0] = srcv[0]; dst[1] = srcv[1]; dst[2] = srcv[2]; dst[3] = srcv[3];

    Spart[t] = s;
    __syncthreads();
    if (t < 128)
        S[pix] = Spart[t] + Spart[t + 128];
}

// ---------------------------------------------------------------------------
// Phase B: 256 threads, 8x16 output tile. Halo 10x18 px bf16 in LDS with
// XOR-granule swizzle (slot = g ^ (p&7)). Wave wv owns pixel-tile wv (32 px,
// 2 rows x 16); each wave computes ALL 128 n_out (4 W-tiles) for its pixels.
// MFMA roles: A = W (m=n_out), B = E (n=pixel). K = 36 chunks of 16,
// prefetch-1 pipeline; W-frags straight from L2-resident Bt2 (1KB/instr).
// Epilogue: per-lane scalar Zinv; stores = full 64B segments.
// ---------------------------------------------------------------------------
__global__ __launch_bounds__(256, 4) void conv3(const uint4* __restrict__ Etu,
                                                const uint4* __restrict__ Bt2,
                                                const float* __restrict__ S,
                                                const uint4* __restrict__ ones,
                                                float* __restrict__ out) {
    __shared__ __align__(16) uint4 EtL[180 * 8];   // 23040 B
    __shared__ float Sh[180];
    __shared__ float Zt[128];

    int bid = blockIdx.x;            // 1024 = 8 b * 16 ty * 8 tx
    int b = bid >> 7;
    int ty = (bid >> 3) & 15, tx = bid & 7;
    int h0 = ty * 8, w0 = tx * 16;
    int t = threadIdx.x;

    // ---- stage Et halo (180 pixels x 8 granules, 16B each) ----
    const uint4* Etb = Etu + (size_t)b * HW * 8;
#pragma unroll
    for (int i = 0; i < 6; i++) {
        int qd = i * 256 + t;
        if (qd < 1440) {
            int p = qd >> 3, slot = qd & 7;
            int py = p / 18, px = p - py * 18;
            int gy = h0 - 1 + py, gx = w0 - 1 + px;
            bool in = (gy >= 0) & (gy < Hn) & (gx >= 0) & (gx < Wn);
            int g = slot ^ (p & 7);
            const uint4* src = in ? (Etb + ((size_t)(gy * Wn + gx)) * 8 + g)
                                  : (ones + g);
            EtL[p * 8 + slot] = *src;
        }
    }
    // ---- stage S halo ----
    if (t < 180) {
        int py = t / 18, px = t - py * 18;
        int gy = h0 - 1 + py, gx = w0 - 1 + px;
        bool in = (gy >= 0) & (gy < Hn) & (gx >= 0) & (gx < Wn);
        Sh[t] = in ? S[(size_t)b * HW + gy * Wn + gx] : 64.0f;
    }
    __syncthreads();

    // ---- Zinv per output pixel ----
    if (t < 128) {
        int zy = t >> 4, zx = t & 15;
        float z = 0.f;
#pragma unroll
        for (int dy = 0; dy < 3; dy++)
#pragma unroll
            for (int dx = 0; dx < 3; dx++)
                z += Sh[(zy + dy) * 18 + (zx + dx)];
        Zt[t] = 1.0f / z;
    }
    __syncthreads();

    // ---- MFMA K-loop ----
    int lane = t & 63, wv = t >> 6;
    int l31 = lane & 31, hi = lane >> 5;
    int y0 = wv * 2 + (l31 >> 4);     // tile row of this lane's pixel
    int x0 = l31 & 15;

    f32x16_t acc[4];
#pragma unroll
    for (int g = 0; g < 4; g++)
#pragma unroll
        for (int r = 0; r < 16; r++) acc[g][r] = 0.f;

    bf16x8_t Wf[2][4], Ef[2];

    auto loadW = [&](int kc, bf16x8_t* Wd) {
        const uint4* bp = Bt2 + (size_t)((kc * 2 + hi) * 128 + l31);
#pragma unroll
        for (int g = 0; g < 4; g++)
            Wd[g] = *(const bf16x8_t*)(bp + g * 32);
    };
    auto loadE = [&](int kc, bf16x8_t& Ed) {
        int q = kc >> 2, cblk = kc & 3;
        int kh = q / 3, kw = q - kh * 3;
        int pix = (y0 + kh) * 18 + (x0 + kw);
        int g = cblk * 2 + hi;
        Ed = *(const bf16x8_t*)&EtL[pix * 8 + (g ^ (pix & 7))];
    };

    loadW(0, Wf[0]);
    loadE(0, Ef[0]);
#pragma unroll
    for (int kc = 0; kc < 36; kc++) {
        int cur = kc & 1, nxt = cur ^ 1;
        if (kc + 1 < 36) {
            loadW(kc + 1, Wf[nxt]);
            loadE(kc + 1, Ef[nxt]);
        }
#pragma unroll
        for (int g = 0; g < 4; g++)
            acc[g] = __builtin_amdgcn_mfma_f32_32x32x16_bf16(Wf[cur][g], Ef[cur], acc[g], 0, 0, 0);
    }

    // ---- epilogue: D col(n)=pixel=l31, row m=n_out=(r&3)+8*(r>>2)+4*hi ----
    float zi = Zt[wv * 32 + l31];
    float* obase = out + (size_t)b * OC * HW + (h0 + y0) * Wn + (w0 + x0)
                 + (size_t)(4 * hi) * HW;
#pragma unroll
    for (int g = 0; g < 4; g++) {
#pragma unroll
        for (int r = 0; r < 16; r++) {
            int nrel = g * 32 + (r & 3) + 8 * (r >> 2);   // + 4*hi in obase
            obase[(size_t)nrel * HW] = acc[g][r] * zi;
        }
    }
}

// ---------------------------------------------------------------------------
extern "C" void kernel_launch(void* const* d_in, const int* in_sizes, int n_in,
                              void* d_out, int out_size, void* d_ws, size_t ws_size,
                              hipStream_t stream) {
    const float* x = (const float*)d_in[0];
    const float* mem = (const float*)d_in[1];
    float* out = (float*)d_out;
    char* ws = (char*)d_ws;

    uint4* Etu = (uint4*)ws;                               // 16,777,216 B
    float* S = (float*)(ws + 16777216);                    //    524,288 B
    uint4* Bt2 = (uint4*)(ws + 17301504);                  //    147,456 B
    uint4* ones = (uint4*)(ws + 17448960);                 //        128 B

    prep_b2<<<37, 256, 0, stream>>>(mem, Bt2, ones);
    exp_tr3<<<1024, 256, 0, stream>>>(x, Etu, S);
    conv3<<<1024, 256, 0, stream>>>(Etu, Bt2, S, ones, out);
}

// Round 5
// 115.990 us; speedup vs baseline: 1.0749x; 1.0749x over previous
//
#include <hip/hip_runtime.h>
#include <stdint.h>

// ConvMemory: out = (3x3 conv of E=exp(x), weights=memory) / (3x3 boxsum of channel-sum(E))
// Zero-padding before softmax => OOB taps contribute exp(0)=1 to num & denom.
// exp_tr4: NCHW f32 -> NHWC bf16 Et (+ per-pixel channel sum S), channel-pair
//   packed LDS transpose (b64 writes, b32 reads, no reconversion).
// conv4: implicit-GEMM conv, mfma_f32_32x32x16_bf16, A=W (m=n_out), B=E
//   (n=pixel). Wave owns 64 px -> 8 MFMA/iter; 3-deep register prefetch
//   pipeline on W (global, L2-hot) and E (LDS, XOR-granule swizzle).

#define Cn 64
#define Hn 128
#define Wn 128
#define OC 128
#define HW (Hn * Wn)

typedef __attribute__((ext_vector_type(8))) short bf16x8_t;
typedef __attribute__((ext_vector_type(4))) float f32x4_t;
typedef __attribute__((ext_vector_type(16))) float f32x16_t;

__device__ inline unsigned short f2bf(float f) {
    union { float f; uint32_t u; } v; v.f = f;
    uint32_t u = v.u;
    u += 0x7fffu + ((u >> 16) & 1u);
    return (unsigned short)(u >> 16);
}
__device__ inline float bf_lo(uint32_t u) {
    union { uint32_t u; float f; } v; v.u = u << 16;
    return v.f;
}
__device__ inline float bf_hi(uint32_t u) {
    union { uint32_t u; float f; } v; v.u = u & 0xffff0000u;
    return v.f;
}

// ---------------------------------------------------------------------------
// prep: memory[576][128] f32 -> Bt2 bf16 chunks: chunk cid=(kc*2+hi), 128 n's,
// 16B per n = 8 channels c = (kc&3)*16 + hi*8 + j, q = kc>>2 (kh*3+kw).
// Block 36 writes the 128B "ones page" (bf16 1.0) used for OOB halo pixels.
// ---------------------------------------------------------------------------
__global__ void prep_b2(const float* __restrict__ mem, uint4* __restrict__ Bt2,
                        uint4* __restrict__ ones) {
    if (blockIdx.x == 36) {
        if (threadIdx.x < 8)
            ones[threadIdx.x] = make_uint4(0x3F803F80u, 0x3F803F80u, 0x3F803F80u, 0x3F803F80u);
        return;
    }
    int u = blockIdx.x * 256 + threadIdx.x;   // 0..9215
    int n = u & 127;
    int cid = u >> 7;                         // 0..71
    int hi = cid & 1;
    int kc = cid >> 1;                        // 0..35
    int q = kc >> 2, cblk = kc & 3;
    unsigned short h8[8];
#pragma unroll
    for (int j = 0; j < 8; j++) {
        int c = cblk * 16 + hi * 8 + j;
        h8[j] = f2bf(mem[(c * 9 + q) * OC + n]);
    }
    Bt2[cid * 128 + n] = *(const uint4*)h8;
}

// ---------------------------------------------------------------------------
// exp_tr4: per (b,h) row. Phase 1: wave wv handles channel pairs cp=wv*8+i;
// lane reads float2 from rows 2cp,2cp+1 (512B/wave coalesced), exps, packs
// (c,c+1) per pixel into u32, ds_write_b64 conflict-free into L[cp][w].
// Rounded-value partial sums -> Spart. Phase 2: thread (w=t>>1, half=t&1)
// reads 16 b32 (already-packed bf16), 4 uint4 stores (line-paired), S reduce.
// ---------------------------------------------------------------------------
__global__ __launch_bounds__(256) void exp_tr4(const float* __restrict__ x,
                                               uint4* __restrict__ Etu,
                                               float* __restrict__ S) {
    __shared__ uint32_t L[32 * 132];     // [cp][w], pad 128->132 u32
    __shared__ float Spart[512];
    int bid = blockIdx.x;            // 1024 = 8 b * 128 h
    int b = bid >> 7, h = bid & 127;
    int t = threadIdx.x;
    int wv = t >> 6, lane = t & 63;

    const float* xr = x + (size_t)b * Cn * HW + h * Wn;
    float s0 = 0.f, s1 = 0.f;
#pragma unroll
    for (int i = 0; i < 8; i++) {
        int cp = wv * 8 + i;
        const float* r0 = xr + (size_t)(2 * cp) * HW + 2 * lane;
        float2 v0 = *(const float2*)r0;
        float2 v1 = *(const float2*)(r0 + HW);
        uint32_t p0 = (uint32_t)f2bf(__expf(v0.x)) | ((uint32_t)f2bf(__expf(v1.x)) << 16);
        uint32_t p1 = (uint32_t)f2bf(__expf(v0.y)) | ((uint32_t)f2bf(__expf(v1.y)) << 16);
        s0 += bf_lo(p0) + bf_hi(p0);
        s1 += bf_lo(p1) + bf_hi(p1);
        *(uint2*)&L[cp * 132 + 2 * lane] = make_uint2(p0, p1);
    }
    *(float2*)&Spart[wv * 128 + 2 * lane] = make_float2(s0, s1);
    __syncthreads();

    int w = t >> 1, half = t & 1;
    uint32_t us[16];
#pragma unroll
    for (int j = 0; j < 16; j++)
        us[j] = L[(half * 16 + j) * 132 + w];
    size_t pix = (size_t)(b * Hn + h) * Wn + w;
    uint4* dst = Etu + pix * 8 + half * 4;
    const uint4* sv = (const uint4*)us;
    dst[0] = sv[0]; dst[1] = sv[1]; dst[2] = sv[2]; dst[3] = sv[3];

    if (half == 0)
        S[pix] = Spart[w] + Spart[128 + w] + Spart[256 + w] + Spart[384 + w];
}

// ---------------------------------------------------------------------------
// conv4: 256 threads, 16x16 output tile (M=pixels 256, all 128 n_out).
// Halo 18x18 px bf16 in LDS, XOR-granule swizzle (slot = g ^ (p&7)).
// Wave wv owns 2 pixel-tiles (64 px); per kc: 4 W frags (global, coalesced
// 1KB) + 2 E frags (LDS b128) -> 8 MFMA. 3-slot register prefetch pipeline.
// Epilogue: per-lane scalar Zinv; 64B-segment stores.
// ---------------------------------------------------------------------------
__global__ __launch_bounds__(256, 2) void conv4(const uint4* __restrict__ Etu,
                                                const uint4* __restrict__ Bt2,
                                                const float* __restrict__ S,
                                                const uint4* __restrict__ ones,
                                                float* __restrict__ out) {
    __shared__ __align__(16) uint4 EtL[324 * 8];   // 41472 B
    __shared__ float Sh[324];
    __shared__ float Zt[256];

    int bid = blockIdx.x;            // 512 = 8 b * 8 ty * 8 tx
    int b = bid >> 6;
    int ty = (bid >> 3) & 7, tx = bid & 7;
    int h0 = ty * 16, w0 = tx * 16;
    int t = threadIdx.x;

    // ---- stage Et halo (324 pixels x 8 granules, 16B each) ----
    const uint4* Etb = Etu + (size_t)b * HW * 8;
#pragma unroll
    for (int i = 0; i < 11; i++) {
        int qd = i * 256 + t;
        if (qd < 2592) {
            int p = qd >> 3, slot = qd & 7;
            int py = p / 18, px = p - py * 18;
            int gy = h0 - 1 + py, gx = w0 - 1 + px;
            bool in = (gy >= 0) & (gy < Hn) & (gx >= 0) & (gx < Wn);
            int g = slot ^ (p & 7);
            const uint4* src = in ? (Etb + ((size_t)(gy * Wn + gx)) * 8 + g)
                                  : (ones + g);
            EtL[p * 8 + slot] = *src;
        }
    }
    // ---- stage S halo ----
#pragma unroll
    for (int i = 0; i < 2; i++) {
        int p = i * 256 + t;
        if (p < 324) {
            int py = p / 18, px = p - py * 18;
            int gy = h0 - 1 + py, gx = w0 - 1 + px;
            bool in = (gy >= 0) & (gy < Hn) & (gx >= 0) & (gx < Wn);
            Sh[p] = in ? S[(size_t)b * HW + gy * Wn + gx] : 64.0f;
        }
    }
    __syncthreads();

    // ---- Zinv per output pixel ----
    {
        int zy = t >> 4, zx = t & 15;
        float z = 0.f;
#pragma unroll
        for (int dy = 0; dy < 3; dy++)
#pragma unroll
            for (int dx = 0; dx < 3; dx++)
                z += Sh[(zy + dy) * 18 + (zx + dx)];
        Zt[t] = 1.0f / z;
    }
    __syncthreads();

    // ---- MFMA K-loop: 36 chunks of K=16, 3-deep prefetch ----
    int lane = t & 63, wv = t >> 6;
    int l31 = lane & 31, hi = lane >> 5;
    int x0v = l31 & 15;
    int y0[2];
    y0[0] = (wv * 2 + 0) * 2 + (l31 >> 4);
    y0[1] = (wv * 2 + 1) * 2 + (l31 >> 4);

    f32x16_t acc[2][4];
#pragma unroll
    for (int j = 0; j < 2; j++)
#pragma unroll
        for (int g = 0; g < 4; g++)
#pragma unroll
            for (int r = 0; r < 16; r++) acc[j][g][r] = 0.f;

    bf16x8_t Wf[3][4], Ef[3][2];

    auto loadW = [&](int kc, int s) {
        const uint4* bp = Bt2 + (size_t)((kc * 2 + hi) * 128 + l31);
#pragma unroll
        for (int g = 0; g < 4; g++)
            Wf[s][g] = *(const bf16x8_t*)(bp + g * 32);
    };
    auto loadE = [&](int kc, int s) {
        int q = kc >> 2, cblk = kc & 3;
        int kh = q / 3, kw = q - kh * 3;
        int g = cblk * 2 + hi;
#pragma unroll
        for (int j = 0; j < 2; j++) {
            int pix = (y0[j] + kh) * 18 + (x0v + kw);
            Ef[s][j] = *(const bf16x8_t*)&EtL[pix * 8 + (g ^ (pix & 7))];
        }
    };

    loadW(0, 0); loadE(0, 0);
    loadW(1, 1); loadE(1, 1);
    loadW(2, 2); loadE(2, 2);
#pragma unroll
    for (int kc = 0; kc < 36; kc++) {
        int s = kc % 3;
#pragma unroll
        for (int g = 0; g < 4; g++)
#pragma unroll
            for (int j = 0; j < 2; j++)
                acc[j][g] = __builtin_amdgcn_mfma_f32_32x32x16_bf16(
                    Wf[s][g], Ef[s][j], acc[j][g], 0, 0, 0);
        if (kc + 3 < 36) { loadW(kc + 3, s); loadE(kc + 3, s); }
    }

    // ---- epilogue: D col(n)=pixel=l31, row m=n_out=(r&3)+8*(r>>2)+4*hi ----
#pragma unroll
    for (int j = 0; j < 2; j++) {
        float zi = Zt[(wv * 2 + j) * 32 + l31];
        float* ob = out + (size_t)b * OC * HW + (h0 + y0[j]) * Wn + (w0 + x0v)
                  + (size_t)(4 * hi) * HW;
#pragma unroll
        for (int g = 0; g < 4; g++) {
#pragma unroll
            for (int r = 0; r < 16; r++) {
                int nrel = g * 32 + (r & 3) + 8 * (r >> 2);   // + 4*hi in ob
                ob[(size_t)nrel * HW] = acc[j][g][r] * zi;
            }
        }
    }
}

// ---------------------------------------------------------------------------
extern "C" void kernel_launch(void* const* d_in, const int* in_sizes, int n_in,
                              void* d_out, int out_size, void* d_ws, size_t ws_size,
                              hipStream_t stream) {
    const float* x = (const float*)d_in[0];
    const float* mem = (const float*)d_in[1];
    float* out = (float*)d_out;
    char* ws = (char*)d_ws;

    uint4* Etu = (uint4*)ws;                               // 16,777,216 B
    float* S = (float*)(ws + 16777216);                    //    524,288 B
    uint4* Bt2 = (uint4*)(ws + 17301504);                  //    147,456 B
    uint4* ones = (uint4*)(ws + 17448960);                 //        128 B

    prep_b2<<<37, 256, 0, stream>>>(mem, Bt2, ones);
    exp_tr4<<<1024, 256, 0, stream>>>(x, Etu, S);
    conv4<<<512, 256, 0, stream>>>(Etu, Bt2, S, ones, out);
}